// Round 1
// baseline (750.074 us; speedup 1.0000x reference)
//
#include <hip/hip_runtime.h>
#include <stdint.h>

// B=4, DIM=256, W0=H0=128, HEADS=8, HEAD_DIM=32, FOLD=2, PROP=4
// 128 folded tiles (bb), each c=32, 64x64 (N=4096), M=16 centers.
// split_mask==0 => 7x7 conv contributes nothing; Wv/bv dead. All I/O f32.
// Pipeline: k0 geo-centers | k1a x-centers | kf fused sim+dnum(MFMA)+denss+out+GN-stats
//           | k2 GN-fold + W*alpha f16 | k3 MFMA proj+SiLU
// kf keeps the whole 4096x16 f16 sim matrix in LDS (128 KB): one block per tile,
// 16 waves, each wave owns px-chunk [w*256, w*256+256). Eliminates g_sim/g_dnum/
// g_rsum global round-trips and two kernel launches.

typedef __attribute__((ext_vector_type(8))) short short8;
typedef __attribute__((ext_vector_type(4))) float floatx4;
typedef __fp16 fp16x2 __attribute__((ext_vector_type(2)));

__device__ float g_sbp[256];                           // per-tile GN partials [bb][2]
__device__ float g_bias[1024];
__device__ __attribute__((aligned(16))) _Float16 g_Wa[4*256*256];   // W*alpha, f16 [b][o][c]
__device__ float g_cenraw[128*16*32];
__device__ float g_cenhat[128*16*32];
__device__ float g_gcenhat[16*16*4];
__device__ __attribute__((aligned(16))) _Float16 g_preout[(size_t)128*4096*32]; // [tile][n][c]

static __device__ __forceinline__ fp16x2 as_h2(unsigned u) { return __builtin_bit_cast(fp16x2, u); }
static __device__ __forceinline__ unsigned pk(float a, float b) {
  return __builtin_bit_cast(unsigned, __builtin_amdgcn_cvt_pkrtz(a, b));
}
#if __has_builtin(__builtin_amdgcn_fdot2)
static __device__ __forceinline__ float fdot2(fp16x2 a, fp16x2 b, float c) {
  return __builtin_amdgcn_fdot2(a, b, c, false);
}
#else
static __device__ __forceinline__ float fdot2(fp16x2 a, fp16x2 b, float c) {
  return c + (float)a[0]*(float)b[0] + (float)a[1]*(float)b[1];
}
#endif
static __device__ __forceinline__ float sum16(const float* p) {
  const float4* q = (const float4*)p;
  float4 a = q[0], b = q[1], c = q[2], d = q[3];
  return (a.x+a.y+a.z+a.w) + (b.x+b.y+b.z+b.w) + (c.x+c.y+c.z+c.w) + (d.x+d.y+d.z+d.w);
}
static __device__ __forceinline__ float sigm(float z) {
  return __builtin_amdgcn_rcpf(1.f + __expf(-z));
}

// ---------------- k0: geo pooled centers ----------------
__global__ __launch_bounds__(64) void k0_geo(const float* __restrict__ xyz) {
  __shared__ float gc[64];
  const int gti = blockIdx.x;
  const int bg = gti >> 2, f1 = (gti >> 1) & 1, f2 = gti & 1;
  const int t = threadIdx.x;
  if (t < 48) {
    const int m = t / 3, ch = t - 3*(t/3);
    const int pi = m >> 2, pj = m & 3;
    const float* p = xyz + (size_t)(bg*3+ch)*16384 + (f1*64 + pi*16)*128 + f2*64 + pj*16;
    float s = 0.f;
    #pragma unroll
    for (int r = 0; r < 16; ++r) s += sum16(p + r*128);
    gc[m*4+ch] = s * (1.f/256.f);
  }
  __syncthreads();
  if (t < 16) {
    float g0 = gc[t*4], g1 = gc[t*4+1], g2 = gc[t*4+2];
    float inv = 1.f / fmaxf(sqrtf(g0*g0+g1*g1+g2*g2), 1e-12f);
    float* o = g_gcenhat + gti*64 + t*4;
    o[0] = g0*inv; o[1] = g1*inv; o[2] = g2*inv; o[3] = 0.f;
  }
}

// ---------------- k1a: x pooled centers + normalize ----------------
__global__ __launch_bounds__(128) void k1a_cen(const float* __restrict__ x) {
  __shared__ float cenL[128];
  __shared__ float invL[4];
  const int blk = blockIdx.x;
  const int bb = blk >> 2, pi = blk & 3;
  const int b = bb >> 5, e = (bb >> 2) & 7, f1 = (bb >> 1) & 1, f2 = bb & 1;
  const int tid = threadIdx.x;
  const int c = tid >> 2, pj = tid & 3;
  const int m = pi*4 + pj;
  const float* p = x + ((size_t)(b*256 + e*32 + c)*128 + f1*64 + pi*16)*128 + f2*64 + pj*16;
  float s = 0.f;
  #pragma unroll
  for (int r = 0; r < 16; ++r) s += sum16(p + r*128);
  const float raw = s * (1.f/256.f);
  cenL[pj*32 + c] = raw;
  g_cenraw[(bb*16 + m)*32 + c] = raw;
  __syncthreads();
  if (tid < 4) {
    float ss = 0.f;
    #pragma unroll
    for (int cc = 0; cc < 32; ++cc) { float v = cenL[tid*32+cc]; ss += v*v; }
    invL[tid] = 1.f / fmaxf(sqrtf(ss), 1e-12f);
  }
  __syncthreads();
  g_cenhat[(bb*16 + m)*32 + c] = raw * invL[pj];
}

// ---------------- kf: fused sim + rowsum + dnum(MFMA) + denss + out + GN stats ----
// One block per tile. 1024 threads = 16 waves; wave w owns px [w*256, w*256+256).
// LDS: sim f16 [n=4096][m=16] packed as u32 pairs = 128 KB (+ ~6 KB scratch).
__global__ __launch_bounds__(1024, 4) void kf_simout(const float* __restrict__ x,
                                                     const float* __restrict__ xyz,
                                                     const float* __restrict__ salpha,
                                                     const float* __restrict__ sbeta) {
  __shared__ __attribute__((aligned(16))) unsigned simL[4096*8]; // 128 KB
  __shared__ unsigned chP[256];        // cen_hat packed [m][cpair]
  __shared__ unsigned dl[256];         // denss packed [c][mpair]
  __shared__ float gcenL[64];
  __shared__ float rsW[16*16];         // [wave][m] rowsum partials
  __shared__ float dnumL[512];         // [m][c] f32
  __shared__ float sred[32];
  const int bb = blockIdx.x;
  const int b = bb >> 5, e = (bb >> 2) & 7, f1 = (bb >> 1) & 1, f2 = bb & 1;
  const int gti = ((e & 3) << 2) | (f1 << 1) | f2;
  const int tid = threadIdx.x, lane = tid & 63, wave = tid >> 6;
  const int lm = lane & 15, quad = lane >> 4;
  const float alpha = salpha[0], beta = sbeta[0];
  const float* xt = x + (((size_t)(b*256 + e*32))*128 + f1*64)*128 + f2*64;
  const float* gxyz = xyz + (size_t)((e & 3)*3)*16384 + f1*8192 + f2*64;

  if (tid < 256) {
    const float2 cp = *(const float2*)(g_cenhat + bb*512 + tid*2);
    chP[tid] = pk(cp.x, cp.y);
  }
  if (tid < 64) gcenL[tid] = g_gcenhat[gti*64 + tid];
  if (tid < 512) dnumL[tid] = 0.f;
  __syncthreads();

  // ---- phase 1: sim (f16 -> LDS) + per-thread rowsum accumulators ----
  float rs[16];
  #pragma unroll
  for (int m = 0; m < 16; ++m) rs[m] = 0.f;

  #pragma unroll
  for (int j = 0; j < 4; ++j) {
    const int px = wave*256 + j*64 + lane;
    const int addr = (wave*4 + j)*128 + lane;     // (px>>6)*128 + (px&63)
    float ss = 0.f;
    unsigned xp[16];
    #pragma unroll
    for (int p = 0; p < 16; ++p) {
      const float v0 = xt[(size_t)(2*p)*16384 + addr];
      const float v1 = xt[(size_t)(2*p+1)*16384 + addr];
      ss += v0*v0 + v1*v1;
      xp[p] = pk(v0, v1);
    }
    const float invn = __builtin_amdgcn_rcpf(fmaxf(sqrtf(ss), 1e-12f));
    float g0, g1, g2;
    {
      const float* gp = gxyz + addr;
      g0 = gp[0]; g1 = gp[16384]; g2 = gp[32768];
      const float invg = __builtin_amdgcn_rcpf(fmaxf(sqrtf(g0*g0+g1*g1+g2*g2), 1e-12f));
      g0 *= invg; g1 *= invg; g2 *= invg;
    }
    unsigned sw[8];
    #pragma unroll
    for (int mp = 0; mp < 8; ++mp) {
      const int m0 = 2*mp, m1 = 2*mp + 1;
      float d0 = 0.f, d1 = 0.f;
      #pragma unroll
      for (int p = 0; p < 16; ++p) {
        const fp16x2 xv = as_h2(xp[p]);
        d0 = fdot2(as_h2(chP[m0*16 + p]), xv, d0);
        d1 = fdot2(as_h2(chP[m1*16 + p]), xv, d1);
      }
      d0 *= invn; d1 *= invn;
      const float* gh0 = gcenL + m0*4;
      const float* gh1 = gcenL + m1*4;
      const float dg0 = gh0[0]*g0 + gh0[1]*g1 + gh0[2]*g2;
      const float dg1 = gh1[0]*g0 + gh1[1]*g1 + gh1[2]*g2;
      const float s0  = sigm(beta + alpha*d0), gg0 = sigm(beta + alpha*dg0);
      const float s1v = sigm(beta + alpha*d1), gg1 = sigm(beta + alpha*dg1);
      const float sv0 = s0*gg0*gg0, sv1 = s1v*gg1*gg1;
      rs[m0] += sv0; rs[m1] += sv1;
      sw[mp] = pk(sv0, sv1);
    }
    *(uint4*)&simL[px*8]     = *(const uint4*)&sw[0];
    *(uint4*)&simL[px*8 + 4] = *(const uint4*)&sw[4];
  }
  #pragma unroll
  for (int m = 0; m < 16; ++m) {
    float v = rs[m];
    #pragma unroll
    for (int off = 1; off < 64; off <<= 1) v += __shfl_xor(v, off, 64);
    if (lane == 0) rsW[wave*16 + m] = v;
  }
  __syncthreads();

  // ---- phase 2a: dnum[m][c] = sum_px sim[px][m]*x[c][px], MFMA over wave's K-chunk
  {
    floatx4 acc0 = {0.f,0.f,0.f,0.f}, acc1 = {0.f,0.f,0.f,0.f};
    const _Float16* simH = (const _Float16*)simL;
    #pragma unroll
    for (int ks = 0; ks < 8; ++ks) {
      const int kb = wave*256 + ks*32 + quad*8;       // px base for this frag slice
      short8 af;
      #pragma unroll
      for (int t = 0; t < 8; ++t)
        af[t] = __builtin_bit_cast(short, simH[(kb + t)*16 + lm]);   // A[m=lm][k=px]
      const int ag = ((kb >> 6)*128) + (kb & 63);
      const float* pb0 = xt + (size_t)lm*16384 + ag;                 // B[k=px][c=lm]
      const float* pb1 = pb0 + (size_t)16*16384;                     // c = lm+16
      short8 bf0, bf1;
      #pragma unroll
      for (int t = 0; t < 8; ++t) bf0[t] = __builtin_bit_cast(short, (_Float16)pb0[t]);
      #pragma unroll
      for (int t = 0; t < 8; ++t) bf1[t] = __builtin_bit_cast(short, (_Float16)pb1[t]);
      acc0 = __builtin_amdgcn_mfma_f32_16x16x32_f16(af, bf0, acc0, 0, 0, 0);
      acc1 = __builtin_amdgcn_mfma_f32_16x16x32_f16(af, bf1, acc1, 0, 0, 0);
    }
    #pragma unroll
    for (int r = 0; r < 4; ++r) {
      const int m = quad*4 + r;                       // C row = m, col = c
      atomicAdd(&dnumL[m*32 + lm],      acc0[r]);
      atomicAdd(&dnumL[m*32 + 16 + lm], acc1[r]);
    }
  }
  __syncthreads();

  // ---- phase 2b: denss = (cenraw + dnum) / (1 + rowsum), packed [c][mpair] ----
  if (tid < 256) {
    const int c = tid >> 3, mp = tid & 7;
    const int m0 = 2*mp, m1 = 2*mp + 1;
    float r0 = 1.f, r1 = 1.f;
    #pragma unroll
    for (int w = 0; w < 16; ++w) { r0 += rsW[w*16 + m0]; r1 += rsW[w*16 + m1]; }
    const float d0 = (g_cenraw[bb*512 + m0*32 + c] + dnumL[m0*32 + c]) / r0;
    const float d1 = (g_cenraw[bb*512 + m1*32 + c] + dnumL[m1*32 + c]) / r1;
    dl[tid] = pk(d0, d1);
  }
  __syncthreads();

  // ---- phase 3: out[px][c] = sum_m sim[px][m]*denss[m][c]; GN stats; f16 preout ----
  float s1 = 0.f, s2 = 0.f;
  #pragma unroll
  for (int j = 0; j < 4; ++j) {
    const int px = wave*256 + j*64 + lane;
    const uint4 q0 = *(const uint4*)&simL[px*8];
    const uint4 q1 = *(const uint4*)&simL[px*8 + 4];
    unsigned sp[8] = {q0.x, q0.y, q0.z, q0.w, q1.x, q1.y, q1.z, q1.w};
    float out[32];
    #pragma unroll
    for (int c = 0; c < 32; ++c) {
      float acc = 0.f;
      #pragma unroll
      for (int mp = 0; mp < 8; ++mp) acc = fdot2(as_h2(sp[mp]), as_h2(dl[c*8 + mp]), acc);
      out[c] = acc; s1 += acc; s2 += acc*acc;
    }
    uint4 w4[4];
    #pragma unroll
    for (int q = 0; q < 4; ++q) {
      w4[q].x = pk(out[8*q+0], out[8*q+1]); w4[q].y = pk(out[8*q+2], out[8*q+3]);
      w4[q].z = pk(out[8*q+4], out[8*q+5]); w4[q].w = pk(out[8*q+6], out[8*q+7]);
    }
    _Float16* gp = g_preout + ((size_t)bb*4096 + px)*32;
    *(uint4*)gp = w4[0]; *(uint4*)(gp+8) = w4[1]; *(uint4*)(gp+16) = w4[2]; *(uint4*)(gp+24) = w4[3];
  }
  #pragma unroll
  for (int off = 1; off < 64; off <<= 1) { s1 += __shfl_xor(s1, off, 64); s2 += __shfl_xor(s2, off, 64); }
  if (lane == 0) { sred[wave] = s1; sred[16 + wave] = s2; }
  __syncthreads();
  if (tid == 0) {
    float a = 0.f, q = 0.f;
    #pragma unroll
    for (int w = 0; w < 16; ++w) { a += sred[w]; q += sred[16 + w]; }
    g_sbp[bb*2]     = a;
    g_sbp[bb*2 + 1] = q;
  }
}

// ---------------- k2: GN fold + bias + W*alpha (f16) ----------------
__global__ __launch_bounds__(256) void k2_prep(const float* __restrict__ Wp,
                                               const float* __restrict__ bpr,
                                               const float* __restrict__ gnw,
                                               const float* __restrict__ gnb) {
  __shared__ float betaL[256];
  __shared__ float alphaL[256];
  __shared__ float S12[2];
  const int b = blockIdx.x, t = threadIdx.x;
  if (t < 64) {
    float v1 = 0.f, v2 = 0.f;
    if (t < 32) { v1 = g_sbp[(b*32 + t)*2]; v2 = g_sbp[(b*32 + t)*2 + 1]; }
    #pragma unroll
    for (int off = 1; off < 64; off <<= 1) { v1 += __shfl_xor(v1, off, 64); v2 += __shfl_xor(v2, off, 64); }
    if (t == 0) { S12[0] = v1; S12[1] = v2; }
  }
  __syncthreads();
  const float S1 = S12[0];
  const float S2 = S12[1];
  const float inv_n = 1.f / 4194304.f;
  const float mu  = S1 * inv_n;
  const float inv = rsqrtf(fmaxf(S2*inv_n - mu*mu, 0.f) + 1e-5f);
  const float a = inv * gnw[t];
  alphaL[t] = a;
  betaL[t] = gnb[t] - mu * a;
  __syncthreads();
  float k = bpr[t];
  const float* wr = Wp + t*256;
  _Float16* wa = g_Wa + ((size_t)b*256 + t)*256;
  for (int c = 0; c < 256; c += 8) {
    const float4 w0 = *(const float4*)(wr + c);
    const float4 w1 = *(const float4*)(wr + c + 4);
    k += w0.x*betaL[c+0] + w0.y*betaL[c+1] + w0.z*betaL[c+2] + w0.w*betaL[c+3]
       + w1.x*betaL[c+4] + w1.y*betaL[c+5] + w1.z*betaL[c+6] + w1.w*betaL[c+7];
    uint4 o;
    o.x = pk(w0.x*alphaL[c+0], w0.y*alphaL[c+1]);
    o.y = pk(w0.z*alphaL[c+2], w0.w*alphaL[c+3]);
    o.z = pk(w1.x*alphaL[c+4], w1.y*alphaL[c+5]);
    o.w = pk(w1.z*alphaL[c+6], w1.w*alphaL[c+7]);
    *(uint4*)(wa + c) = o;
  }
  g_bias[b*256 + t] = k;
}

// ---------------- k3: f16 MFMA projection + SiLU, zero LDS staging ----------------
__global__ __launch_bounds__(256, 4) void k3_proj(float* __restrict__ out) {
  __shared__ float biasL[256];
  const int blk = blockIdx.x;
  const int b = blk >> 8, pb = blk & 255;
  const int f1 = pb >> 7, f2 = pb & 1;
  const int nbase = ((pb >> 1) & 63) * 64;
  const int tid = threadIdx.x, lane = tid & 63, wave = tid >> 6;
  const int lm = lane & 15, quad = lane >> 4;
  const int m0 = wave*64;
  biasL[tid] = g_bias[b*256 + tid];
  __syncthreads();
  floatx4 acc[4][4] = {};
  #pragma unroll
  for (int ks = 0; ks < 8; ++ks) {
    const _Float16* bbase = g_preout
        + ((size_t)(b*32 + ks*4 + f1*2 + f2)*4096 + nbase)*32 + quad*8;
    const _Float16* abase = g_Wa + ((size_t)b*256)*256 + (size_t)ks*32 + quad*8;
    short8 afr[4], bfr[4];
    #pragma unroll
    for (int mi = 0; mi < 4; ++mi)
      afr[mi] = *(const short8*)(abase + (size_t)(m0 + mi*16 + lm)*256);
    #pragma unroll
    for (int ni = 0; ni < 4; ++ni)
      bfr[ni] = *(const short8*)(bbase + (ni*16 + lm)*32);
    #pragma unroll
    for (int mi = 0; mi < 4; ++mi) {
      #pragma unroll
      for (int ni = 0; ni < 4; ++ni)
        acc[mi][ni] = __builtin_amdgcn_mfma_f32_16x16x32_f16(afr[mi], bfr[ni], acc[mi][ni], 0, 0, 0);
    }
  }
  #pragma unroll
  for (int mi = 0; mi < 4; ++mi) {
    #pragma unroll
    for (int r = 0; r < 4; ++r) {
      const int o = m0 + mi*16 + quad*4 + r;
      const float kb = biasL[o];
      #pragma unroll
      for (int ni = 0; ni < 4; ++ni) {
        float val = acc[mi][ni][r] + kb;
        val = val * sigm(val);   // SiLU
        out[((size_t)(b*256 + o))*16384 + pb*64 + ni*16 + lm] = val;
      }
    }
  }
}

extern "C" void kernel_launch(void* const* d_in, const int* in_sizes, int n_in,
                              void* d_out, int out_size, void* d_ws, size_t ws_size,
                              hipStream_t stream)
{
  (void)in_sizes; (void)n_in; (void)d_ws; (void)ws_size; (void)out_size;
  const float* x     = (const float*)d_in[0];
  const float* xyz   = (const float*)d_in[1];
  const float* Wproj = (const float*)d_in[4];
  const float* bproj = (const float*)d_in[5];
  const float* gnw   = (const float*)d_in[6];
  const float* gnb   = (const float*)d_in[7];
  const float* sa    = (const float*)d_in[8];
  const float* sb    = (const float*)d_in[9];
  float* out = (float*)d_out;

  hipLaunchKernelGGL(k0_geo,    dim3(16),   dim3(64),   0, stream, xyz);
  hipLaunchKernelGGL(k1a_cen,   dim3(512),  dim3(128),  0, stream, x);
  hipLaunchKernelGGL(kf_simout, dim3(128),  dim3(1024), 0, stream, x, xyz, sa, sb);
  hipLaunchKernelGGL(k2_prep,   dim3(4),    dim3(256),  0, stream, Wproj, bproj, gnw, gnb);
  hipLaunchKernelGGL(k3_proj,   dim3(1024), dim3(256),  0, stream, out);
}

// Round 2
// 250.931 us; speedup vs baseline: 2.9892x; 2.9892x over previous
//
#include <hip/hip_runtime.h>
#include <stdint.h>

// B=4, DIM=256, W0=H0=128, HEADS=8, HEAD_DIM=32, FOLD=2, PROP=4
// 128 folded tiles (bb), each c=32, 64x64 (N=4096), M=16 centers.
// split_mask==0 => 7x7 conv contributes nothing; Wv/bv dead. All I/O f32.
// Pipeline: k0 geo-centers | k1a x-centers | k1b MFMA sim+rowsum+dnum partials
//           | k1c reduce | k1d out+GN-stats | k2 GN-fold + W*alpha f16 | k3 MFMA proj+SiLU
// Round-2: k1b rebuilt around mfma_f32_16x16x32_f16 (sim and dnum), LDS-staged
// operands with conflict-free padded strides. 40960 B LDS -> 4 blocks/CU.

typedef __attribute__((ext_vector_type(8))) short short8;
typedef __attribute__((ext_vector_type(4))) float floatx4;
typedef __fp16 fp16x2 __attribute__((ext_vector_type(2)));

#define SIMW 264     // padded half stride for [16][px] LDS tiles (528 B, 16B-aligned, 2-way banks)

__device__ float g_sbp[2048*2];                        // per-(tile,chunk) GN partials
__device__ float g_alpha[1024];
__device__ float g_bias[1024];
__device__ __attribute__((aligned(16))) _Float16 g_Wa[4*256*256];   // W*alpha, f16 [b][o][c]
__device__ float g_cenraw[128*16*32];
__device__ float g_cenhat[128*16*32];
__device__ float g_gcenhat[16*16*4];
__device__ __attribute__((aligned(16))) _Float16 g_sim[(size_t)128*4096*16];   // [tile][n][m]
__device__ float g_dnum[128*16*16*32];                 // [tile][chunk][m][c]
__device__ float g_rsum[128*16*16];
__device__ unsigned g_dnh2[128*256];                   // denss packed half2 [tile][c][mpair]
__device__ __attribute__((aligned(16))) _Float16 g_preout[(size_t)128*4096*32]; // [tile][n][c]

static __device__ __forceinline__ fp16x2 as_h2(unsigned u) { return __builtin_bit_cast(fp16x2, u); }
static __device__ __forceinline__ unsigned pk(float a, float b) {
  return __builtin_bit_cast(unsigned, __builtin_amdgcn_cvt_pkrtz(a, b));
}
#if __has_builtin(__builtin_amdgcn_fdot2)
static __device__ __forceinline__ float fdot2(fp16x2 a, fp16x2 b, float c) {
  return __builtin_amdgcn_fdot2(a, b, c, false);
}
#else
static __device__ __forceinline__ float fdot2(fp16x2 a, fp16x2 b, float c) {
  return c + (float)a[0]*(float)b[0] + (float)a[1]*(float)b[1];
}
#endif
static __device__ __forceinline__ float sum16(const float* p) {
  const float4* q = (const float4*)p;
  float4 a = q[0], b = q[1], c = q[2], d = q[3];
  return (a.x+a.y+a.z+a.w) + (b.x+b.y+b.z+b.w) + (c.x+c.y+c.z+c.w) + (d.x+d.y+d.z+d.w);
}
static __device__ __forceinline__ float sigm(float z) {
  return __builtin_amdgcn_rcpf(1.f + __expf(-z));
}

// ---------------- k0: geo pooled centers ----------------
__global__ __launch_bounds__(64) void k0_geo(const float* __restrict__ xyz) {
  __shared__ float gc[64];
  const int gti = blockIdx.x;
  const int bg = gti >> 2, f1 = (gti >> 1) & 1, f2 = gti & 1;
  const int t = threadIdx.x;
  if (t < 48) {
    const int m = t / 3, ch = t - 3*(t/3);
    const int pi = m >> 2, pj = m & 3;
    const float* p = xyz + (size_t)(bg*3+ch)*16384 + (f1*64 + pi*16)*128 + f2*64 + pj*16;
    float s = 0.f;
    #pragma unroll
    for (int r = 0; r < 16; ++r) s += sum16(p + r*128);
    gc[m*4+ch] = s * (1.f/256.f);
  }
  __syncthreads();
  if (t < 16) {
    float g0 = gc[t*4], g1 = gc[t*4+1], g2 = gc[t*4+2];
    float inv = 1.f / fmaxf(sqrtf(g0*g0+g1*g1+g2*g2), 1e-12f);
    float* o = g_gcenhat + gti*64 + t*4;
    o[0] = g0*inv; o[1] = g1*inv; o[2] = g2*inv; o[3] = 0.f;
  }
}

// ---------------- k1a: x pooled centers + normalize ----------------
__global__ __launch_bounds__(128) void k1a_cen(const float* __restrict__ x) {
  __shared__ float cenL[128];
  __shared__ float invL[4];
  const int blk = blockIdx.x;
  const int bb = blk >> 2, pi = blk & 3;
  const int b = bb >> 5, e = (bb >> 2) & 7, f1 = (bb >> 1) & 1, f2 = bb & 1;
  const int tid = threadIdx.x;
  const int c = tid >> 2, pj = tid & 3;
  const int m = pi*4 + pj;
  const float* p = x + ((size_t)(b*256 + e*32 + c)*128 + f1*64 + pi*16)*128 + f2*64 + pj*16;
  float s = 0.f;
  #pragma unroll
  for (int r = 0; r < 16; ++r) s += sum16(p + r*128);
  const float raw = s * (1.f/256.f);
  cenL[pj*32 + c] = raw;
  g_cenraw[(bb*16 + m)*32 + c] = raw;
  __syncthreads();
  if (tid < 4) {
    float ss = 0.f;
    #pragma unroll
    for (int cc = 0; cc < 32; ++cc) { float v = cenL[tid*32+cc]; ss += v*v; }
    invL[tid] = 1.f / fmaxf(sqrtf(ss), 1e-12f);
  }
  __syncthreads();
  g_cenhat[(bb*16 + m)*32 + c] = raw * invL[pj];
}

// ---------------- k1b: MFMA sim + rowsum + dnum partials ----------------
// 2048 blocks (tile x 16 chunks of 256 px), 256 threads = 4 waves.
// LDS layouts (all padded to 2-way-max bank aliasing):
//   xL  [px][20 u32]: cpairs 0..15 (f16), dword16 = invn bits  (80 B rows)
//   simS/gT [16][264] f16 (528 B rows)
__global__ __launch_bounds__(256, 4) void k1b_sim(const float* __restrict__ x,
                                                  const float* __restrict__ xyz,
                                                  const float* __restrict__ salpha,
                                                  const float* __restrict__ sbeta) {
  __shared__ __attribute__((aligned(16))) unsigned  xL[256*20];    // 20 KB
  __shared__ __attribute__((aligned(16))) _Float16 simS[16*SIMW];  // 8.25 KB
  __shared__ __attribute__((aligned(16))) _Float16 gT[16*SIMW];    // 8.25 KB  gg^2
  __shared__ __attribute__((aligned(16))) unsigned chP[16*16];     // cen_hat [m][cpair]
  __shared__ float gcenL[64];
  __shared__ float rsW[4*16];
  __shared__ float dnumL[512];
  const int blk = blockIdx.x;
  const int bb = blk >> 4, ck = blk & 15;
  const int b = bb >> 5, e = (bb >> 2) & 7, f1 = (bb >> 1) & 1, f2 = bb & 1;
  const int gti = ((e & 3) << 2) | (f1 << 1) | f2;
  const int tid = threadIdx.x, lane = tid & 63, wave = tid >> 6;
  const int lm = lane & 15, quad = lane >> 4;
  const float alpha = salpha[0], beta = sbeta[0];
  const float* xt = x + (((size_t)(b*256 + e*32))*128 + f1*64)*128 + f2*64;

  {
    const float2 cp = *(const float2*)(g_cenhat + bb*512 + tid*2);
    chP[tid] = pk(cp.x, cp.y);
  }
  if (tid < 64) gcenL[tid] = g_gcenhat[gti*64 + tid];
  dnumL[tid] = 0.f; dnumL[tid + 256] = 0.f;
  __syncthreads();

  // ---- phase 1: load own pixel, pack f16 -> xL, invn, geo gg^2 -> gT ----
  const int ng = ck*256 + tid;
  const int wi = ng >> 6, hi = ng & 63;
  const int addr = wi*128 + hi;
  {
    float ss = 0.f;
    unsigned xp[16];
    #pragma unroll
    for (int p = 0; p < 16; ++p) {
      const float v0 = xt[(size_t)(2*p)*16384 + addr];
      const float v1 = xt[(size_t)(2*p+1)*16384 + addr];
      ss += v0*v0 + v1*v1;
      xp[p] = pk(v0, v1);
    }
    uint4 u0 = {xp[0],xp[1],xp[2],xp[3]};
    uint4 u1 = {xp[4],xp[5],xp[6],xp[7]};
    uint4 u2 = {xp[8],xp[9],xp[10],xp[11]};
    uint4 u3 = {xp[12],xp[13],xp[14],xp[15]};
    *(uint4*)(xL + tid*20)      = u0;
    *(uint4*)(xL + tid*20 + 4)  = u1;
    *(uint4*)(xL + tid*20 + 8)  = u2;
    *(uint4*)(xL + tid*20 + 12) = u3;
    const float invn = __builtin_amdgcn_rcpf(fmaxf(sqrtf(ss), 1e-12f));
    ((float*)xL)[tid*20 + 16] = invn;
  }
  {
    const float* gp = xyz + (size_t)((e & 3)*3)*16384 + (f1*64 + wi)*128 + f2*64 + hi;
    float g0 = gp[0], g1 = gp[16384], g2 = gp[32768];
    const float invg = __builtin_amdgcn_rcpf(fmaxf(sqrtf(g0*g0+g1*g1+g2*g2), 1e-12f));
    g0 *= invg; g1 *= invg; g2 *= invg;
    #pragma unroll
    for (int m = 0; m < 16; ++m) {
      const float* gh = gcenL + m*4;
      const float dg = gh[0]*g0 + gh[1]*g1 + gh[2]*g2;
      const float gg = sigm(beta + alpha*dg);
      gT[m*SIMW + tid] = (_Float16)(gg*gg);
    }
  }
  __syncthreads();

  // ---- phase 2: sim via MFMA (A=cen_hat[m][c], B=x_f16[px][c], K=32) ----
  // k3-verified convention: A-frag row=lm, k=quad*8+t; C[i=quad*4+r][j=lm].
  {
    const short8 afx = *(const short8*)((const _Float16*)chP + lm*32 + quad*8);
    float rsacc[4] = {0.f, 0.f, 0.f, 0.f};
    #pragma unroll
    for (int t = 0; t < 4; ++t) {
      const int px = wave*64 + t*16 + lm;
      const short8 bfx = *(const short8*)((const _Float16*)xL + px*40 + quad*8);
      floatx4 d = {0.f,0.f,0.f,0.f};
      d = __builtin_amdgcn_mfma_f32_16x16x32_f16(afx, bfx, d, 0, 0, 0);
      const float invn = ((const float*)xL)[px*20 + 16];
      #pragma unroll
      for (int r = 0; r < 4; ++r) {
        const int m = quad*4 + r;
        const float gg2 = (float)gT[m*SIMW + px];
        const float sv = sigm(beta + alpha * d[r] * invn) * gg2;
        rsacc[r] += sv;
        simS[m*SIMW + px] = (_Float16)sv;
      }
    }
    #pragma unroll
    for (int r = 0; r < 4; ++r) {
      float v = rsacc[r];
      v += __shfl_xor(v, 1, 64); v += __shfl_xor(v, 2, 64);
      v += __shfl_xor(v, 4, 64); v += __shfl_xor(v, 8, 64);
      if (lm == 0) rsW[wave*16 + quad*4 + r] = v;
    }
  }
  __syncthreads();

  // ---- phase 3a: export sim f16 [px][m] to global for k1d ----
  {
    unsigned w[8];
    const unsigned short* sp = (const unsigned short*)simS;
    #pragma unroll
    for (int p = 0; p < 8; ++p)
      w[p] = (unsigned)sp[(2*p)*SIMW + tid] | ((unsigned)sp[(2*p+1)*SIMW + tid] << 16);
    _Float16* gp = g_sim + ((size_t)bb*4096 + ng)*16;
    *(uint4*)gp       = *(const uint4*)&w[0];
    *(uint4*)(gp + 8) = *(const uint4*)&w[4];
  }
  if (tid < 16)
    g_rsum[(bb*16 + ck)*16 + tid] = rsW[tid] + rsW[16+tid] + rsW[32+tid] + rsW[48+tid];

  // ---- phase 3b: dnum[m][c] partials via MFMA (A=sim[m][px], B=x[c][px], K=px) ----
  {
    floatx4 acc0 = {0.f,0.f,0.f,0.f}, acc1 = {0.f,0.f,0.f,0.f};
    #pragma unroll
    for (int ks = 0; ks < 2; ++ks) {
      const int kb = wave*64 + ks*32 + quad*8;                  // local px base
      const short8 af = *(const short8*)(simS + lm*SIMW + kb);  // A[m=lm][k=px]
      const int ag = ck*512 + ((kb >> 6)*128) + (kb & 63);
      const float* pb0 = xt + (size_t)lm*16384 + ag;            // B[c=lm][k=px]
      const float* pb1 = pb0 + (size_t)16*16384;                // c = lm+16
      short8 bf0, bf1;
      #pragma unroll
      for (int t = 0; t < 8; ++t) bf0[t] = __builtin_bit_cast(short, (_Float16)pb0[t]);
      #pragma unroll
      for (int t = 0; t < 8; ++t) bf1[t] = __builtin_bit_cast(short, (_Float16)pb1[t]);
      acc0 = __builtin_amdgcn_mfma_f32_16x16x32_f16(af, bf0, acc0, 0, 0, 0);
      acc1 = __builtin_amdgcn_mfma_f32_16x16x32_f16(af, bf1, acc1, 0, 0, 0);
    }
    #pragma unroll
    for (int r = 0; r < 4; ++r) {
      atomicAdd(&dnumL[(quad*4 + r)*32 + lm],      acc0[r]);
      atomicAdd(&dnumL[(quad*4 + r)*32 + 16 + lm], acc1[r]);
    }
  }
  __syncthreads();
  g_dnum[(size_t)(bb*16 + ck)*512 + tid]       = dnumL[tid];
  g_dnum[(size_t)(bb*16 + ck)*512 + 256 + tid] = dnumL[tid + 256];
}

// ---------------- k1c: reduce chunk partials -> denss (packed half2) ----------------
__global__ __launch_bounds__(512) void k1c_red() {
  __shared__ float denssL[512];
  __shared__ float rsL[16];
  const int bb = blockIdx.x, tid = threadIdx.x;
  if (tid < 16) {
    float r = 1.f;
    #pragma unroll
    for (int k = 0; k < 16; ++k) r += g_rsum[(bb*16 + k)*16 + tid];
    rsL[tid] = r;
  }
  float a = g_cenraw[bb*512 + tid];
  #pragma unroll
  for (int k = 0; k < 16; ++k) a += g_dnum[(size_t)bb*8192 + k*512 + tid];
  __syncthreads();
  denssL[tid] = a / rsL[tid >> 5];       // tid = m*32 + c
  __syncthreads();
  if (tid < 256) {
    const int c = tid >> 3, mp = tid & 7;
    g_dnh2[bb*256 + c*8 + mp] = pk(denssL[(2*mp)*32 + c], denssL[(2*mp+1)*32 + c]);
  }
}

// ---------------- k1d: out = denss^T sim, GN partials, f16 preout ----------------
__global__ __launch_bounds__(256, 4) void k1d_out() {
  __shared__ unsigned dl[256];   // denss packed [c][mpair]
  __shared__ float sred[8];
  const int blk = blockIdx.x;
  const int bb = blk >> 4, ck = blk & 15;
  const int tid = threadIdx.x, lane = tid & 63, wave = tid >> 6;
  dl[tid] = g_dnh2[bb*256 + tid];
  __syncthreads();
  const int ng = ck*256 + tid;
  unsigned sp[8];
  {
    const _Float16* gp = g_sim + ((size_t)bb*4096 + ng)*16;
    const uint4 q0 = *(const uint4*)gp;
    const uint4 q1 = *(const uint4*)(gp + 8);
    sp[0]=q0.x; sp[1]=q0.y; sp[2]=q0.z; sp[3]=q0.w;
    sp[4]=q1.x; sp[5]=q1.y; sp[6]=q1.z; sp[7]=q1.w;
  }
  float out[32];
  #pragma unroll
  for (int c = 0; c < 32; ++c) {
    float acc = 0.f;
    #pragma unroll
    for (int mp = 0; mp < 8; ++mp) acc = fdot2(as_h2(sp[mp]), as_h2(dl[c*8 + mp]), acc);
    out[c] = acc;
  }
  float s1 = 0.f, s2 = 0.f;
  #pragma unroll
  for (int c = 0; c < 32; ++c) { s1 += out[c]; s2 += out[c]*out[c]; }
  {
    uint4 w[4];
    #pragma unroll
    for (int q = 0; q < 4; ++q) {
      w[q].x = pk(out[8*q+0], out[8*q+1]); w[q].y = pk(out[8*q+2], out[8*q+3]);
      w[q].z = pk(out[8*q+4], out[8*q+5]); w[q].w = pk(out[8*q+6], out[8*q+7]);
    }
    _Float16* gp = g_preout + ((size_t)bb*4096 + ng)*32;
    *(uint4*)gp = w[0]; *(uint4*)(gp+8) = w[1]; *(uint4*)(gp+16) = w[2]; *(uint4*)(gp+24) = w[3];
  }
  #pragma unroll
  for (int off = 1; off < 64; off <<= 1) { s1 += __shfl_xor(s1, off, 64); s2 += __shfl_xor(s2, off, 64); }
  if (lane == 0) { sred[wave] = s1; sred[4+wave] = s2; }
  __syncthreads();
  if (tid == 0) {
    g_sbp[blk*2]   = sred[0]+sred[1]+sred[2]+sred[3];
    g_sbp[blk*2+1] = sred[4]+sred[5]+sred[6]+sred[7];
  }
}

// ---------------- k2: GN fold + bias + W*alpha (f16) ----------------
__global__ __launch_bounds__(256) void k2_prep(const float* __restrict__ Wp,
                                               const float* __restrict__ bpr,
                                               const float* __restrict__ gnw,
                                               const float* __restrict__ gnb) {
  __shared__ float betaL[256];
  __shared__ float alphaL[256];
  __shared__ float rr[8];
  const int b = blockIdx.x, t = threadIdx.x, lane = t & 63, wave = t >> 6;
  float s1 = g_sbp[(b*512 + t)*2]     + g_sbp[(b*512 + 256 + t)*2];
  float s2 = g_sbp[(b*512 + t)*2 + 1] + g_sbp[(b*512 + 256 + t)*2 + 1];
  #pragma unroll
  for (int off = 1; off < 64; off <<= 1) { s1 += __shfl_xor(s1, off, 64); s2 += __shfl_xor(s2, off, 64); }
  if (lane == 0) { rr[wave] = s1; rr[4+wave] = s2; }
  __syncthreads();
  const float S1 = rr[0]+rr[1]+rr[2]+rr[3];
  const float S2 = rr[4]+rr[5]+rr[6]+rr[7];
  const float inv_n = 1.f / 4194304.f;
  const float mu  = S1 * inv_n;
  const float inv = rsqrtf(fmaxf(S2*inv_n - mu*mu, 0.f) + 1e-5f);
  const float a = inv * gnw[t];
  g_alpha[b*256 + t] = a;
  alphaL[t] = a;
  betaL[t] = gnb[t] - mu * a;
  __syncthreads();
  float k = bpr[t];
  const float* wr = Wp + t*256;
  _Float16* wa = g_Wa + ((size_t)b*256 + t)*256;
  for (int c = 0; c < 256; c += 8) {
    const float4 w0 = *(const float4*)(wr + c);
    const float4 w1 = *(const float4*)(wr + c + 4);
    k += w0.x*betaL[c+0] + w0.y*betaL[c+1] + w0.z*betaL[c+2] + w0.w*betaL[c+3]
       + w1.x*betaL[c+4] + w1.y*betaL[c+5] + w1.z*betaL[c+6] + w1.w*betaL[c+7];
    uint4 o;
    o.x = pk(w0.x*alphaL[c+0], w0.y*alphaL[c+1]);
    o.y = pk(w0.z*alphaL[c+2], w0.w*alphaL[c+3]);
    o.z = pk(w1.x*alphaL[c+4], w1.y*alphaL[c+5]);
    o.w = pk(w1.z*alphaL[c+6], w1.w*alphaL[c+7]);
    *(uint4*)(wa + c) = o;
  }
  g_bias[b*256 + t] = k;
}

// ---------------- k3: f16 MFMA projection + SiLU, zero LDS staging ----------------
__global__ __launch_bounds__(256, 4) void k3_proj(float* __restrict__ out) {
  __shared__ float biasL[256];
  const int blk = blockIdx.x;
  const int b = blk >> 8, pb = blk & 255;
  const int f1 = pb >> 7, f2 = pb & 1;
  const int nbase = ((pb >> 1) & 63) * 64;
  const int tid = threadIdx.x, lane = tid & 63, wave = tid >> 6;
  const int lm = lane & 15, quad = lane >> 4;
  const int m0 = wave*64;
  biasL[tid] = g_bias[b*256 + tid];
  __syncthreads();
  floatx4 acc[4][4] = {};
  #pragma unroll
  for (int ks = 0; ks < 8; ++ks) {
    const _Float16* bbase = g_preout
        + ((size_t)(b*32 + ks*4 + f1*2 + f2)*4096 + nbase)*32 + quad*8;
    const _Float16* abase = g_Wa + ((size_t)b*256)*256 + (size_t)ks*32 + quad*8;
    short8 afr[4], bfr[4];
    #pragma unroll
    for (int mi = 0; mi < 4; ++mi)
      afr[mi] = *(const short8*)(abase + (size_t)(m0 + mi*16 + lm)*256);
    #pragma unroll
    for (int ni = 0; ni < 4; ++ni)
      bfr[ni] = *(const short8*)(bbase + (ni*16 + lm)*32);
    #pragma unroll
    for (int mi = 0; mi < 4; ++mi) {
      #pragma unroll
      for (int ni = 0; ni < 4; ++ni)
        acc[mi][ni] = __builtin_amdgcn_mfma_f32_16x16x32_f16(afr[mi], bfr[ni], acc[mi][ni], 0, 0, 0);
    }
  }
  #pragma unroll
  for (int mi = 0; mi < 4; ++mi) {
    #pragma unroll
    for (int r = 0; r < 4; ++r) {
      const int o = m0 + mi*16 + quad*4 + r;
      const float kb = biasL[o];
      #pragma unroll
      for (int ni = 0; ni < 4; ++ni) {
        float val = acc[mi][ni][r] + kb;
        val = val * sigm(val);   // SiLU
        out[((size_t)(b*256 + o))*16384 + pb*64 + ni*16 + lm] = val;
      }
    }
  }
}

extern "C" void kernel_launch(void* const* d_in, const int* in_sizes, int n_in,
                              void* d_out, int out_size, void* d_ws, size_t ws_size,
                              hipStream_t stream)
{
  (void)in_sizes; (void)n_in; (void)d_ws; (void)ws_size; (void)out_size;
  const float* x     = (const float*)d_in[0];
  const float* xyz   = (const float*)d_in[1];
  const float* Wproj = (const float*)d_in[4];
  const float* bproj = (const float*)d_in[5];
  const float* gnw   = (const float*)d_in[6];
  const float* gnb   = (const float*)d_in[7];
  const float* sa    = (const float*)d_in[8];
  const float* sb    = (const float*)d_in[9];
  float* out = (float*)d_out;

  hipLaunchKernelGGL(k0_geo,  dim3(16),   dim3(64),  0, stream, xyz);
  hipLaunchKernelGGL(k1a_cen, dim3(512),  dim3(128), 0, stream, x);
  hipLaunchKernelGGL(k1b_sim, dim3(2048), dim3(256), 0, stream, x, xyz, sa, sb);
  hipLaunchKernelGGL(k1c_red, dim3(128),  dim3(512), 0, stream);
  hipLaunchKernelGGL(k1d_out, dim3(2048), dim3(256), 0, stream);
  hipLaunchKernelGGL(k2_prep, dim3(4),    dim3(256), 0, stream, Wproj, bproj, gnw, gnb);
  hipLaunchKernelGGL(k3_proj, dim3(1024), dim3(256), 0, stream, out);
}